// Round 1
// baseline (34.214 us; speedup 1.0000x reference)
//
#include <hip/hip_runtime.h>

#define NATOMS 8192
#define NFREE  4096

constexpr int TPB = 256;   // threads per block (4 waves)
constexpr int IPT = 4;     // i-atoms per thread
constexpr int TI  = TPB * IPT;   // 1024 i per block
constexpr int JT  = 64;          // j-tile staged in LDS

__device__ __forceinline__ float wave_reduce(float v) {
#pragma unroll
    for (int off = 32; off > 0; off >>= 1)
        v += __shfl_down(v, off, 64);
    return v;
}

// Copy x0 (AoS [N,3]) into SoA X/Y/Z in workspace.
__global__ void build_x(const float* __restrict__ x0,
                        float* __restrict__ X, float* __restrict__ Y, float* __restrict__ Z) {
    int i = blockIdx.x * blockDim.x + threadIdx.x;
    if (i < NATOMS) {
        X[i] = x0[3 * i + 0];
        Y[i] = x0[3 * i + 1];
        Z[i] = x0[3 * i + 2];
    }
}

// Scatter q into X/Y/Z at free_idx, and compute per-block partial sums of qd^2.
__global__ void scatter_q_and_T(const float* __restrict__ q, const float* __restrict__ qd,
                                const int* __restrict__ free_idx,
                                float* __restrict__ X, float* __restrict__ Y, float* __restrict__ Z,
                                float* __restrict__ tpart) {
    int t = blockIdx.x * blockDim.x + threadIdx.x;
    float tq = 0.f;
    if (t < NFREE) {
        int i = free_idx[t];
        X[i] = q[3 * t + 0];
        Y[i] = q[3 * t + 1];
        Z[i] = q[3 * t + 2];
        float a = qd[3 * t + 0], b = qd[3 * t + 1], c = qd[3 * t + 2];
        tq = a * a + b * b + c * c;
    }
    tq = wave_reduce(tq);
    __shared__ float s[TPB / 64];
    int lane = threadIdx.x & 63, wid = threadIdx.x >> 6;
    if (lane == 0) s[wid] = tq;
    __syncthreads();
    if (threadIdx.x == 0)
        tpart[blockIdx.x] = (s[0] + s[1]) + (s[2] + s[3]);
}

// All-pairs 1/r sum. Each block: TI i-atoms x one JT j-slab. Per-block partial out.
__global__ __launch_bounds__(TPB) void pair_kernel(const float* __restrict__ X,
                                                   const float* __restrict__ Y,
                                                   const float* __restrict__ Z,
                                                   float* __restrict__ vpart) {
    __shared__ float sx[JT], sy[JT], sz[JT];
    const int i0 = blockIdx.x * TI;
    const int j0 = blockIdx.y * JT;
    const int t  = threadIdx.x;

    if (t < JT) {
        sx[t] = X[j0 + t];
        sy[t] = Y[j0 + t];
        sz[t] = Z[j0 + t];
    }

    float xi[IPT], yi[IPT], zi[IPT], acc[IPT];
#pragma unroll
    for (int k = 0; k < IPT; ++k) {
        int i = i0 + t + k * TPB;
        xi[k] = X[i];
        yi[k] = Y[i];
        zi[k] = Z[i];
        acc[k] = 0.f;
    }
    __syncthreads();

    if (j0 >= i0 && j0 < i0 + TI) {
        // This j-slab can contain i==j pairs: per-pair select.
#pragma unroll 4
        for (int j = 0; j < JT; ++j) {
            float xj = sx[j], yj = sy[j], zj = sz[j];
            int rel = (j0 + j) - i0;  // i == j  <=>  t + k*TPB == rel
#pragma unroll
            for (int k = 0; k < IPT; ++k) {
                float dx = xi[k] - xj, dy = yi[k] - yj, dz = zi[k] - zj;
                float r2 = fmaf(dx, dx, fmaf(dy, dy, dz * dz));
                float rinv = __builtin_amdgcn_rsqf(fmaxf(r2, 1e-12f));
                acc[k] += (t + k * TPB == rel) ? 0.f : rinv;
            }
        }
    } else {
#pragma unroll 4
        for (int j = 0; j < JT; ++j) {
            float xj = sx[j], yj = sy[j], zj = sz[j];
#pragma unroll
            for (int k = 0; k < IPT; ++k) {
                float dx = xi[k] - xj, dy = yi[k] - yj, dz = zi[k] - zj;
                float r2 = fmaf(dx, dx, fmaf(dy, dy, dz * dz));
                acc[k] += __builtin_amdgcn_rsqf(fmaxf(r2, 1e-12f));
            }
        }
    }

    float v = (acc[0] + acc[1]) + (acc[2] + acc[3]);
    v = wave_reduce(v);
    __shared__ float s[TPB / 64];
    int lane = t & 63, wid = t >> 6;
    if (lane == 0) s[wid] = v;
    __syncthreads();
    if (t == 0)
        vpart[blockIdx.y * gridDim.x + blockIdx.x] = (s[0] + s[1]) + (s[2] + s[3]);
}

// out = 0.5 * sum(tpart) - sum(vpart); deterministic single-block reduction.
__global__ void finalize(const float* __restrict__ vpart, int nv,
                         const float* __restrict__ tpart, int nt,
                         float* __restrict__ out) {
    float v = 0.f;
    for (int i = threadIdx.x; i < nv; i += TPB) v += vpart[i];
    v = wave_reduce(v);
    __shared__ float s[TPB / 64];
    int lane = threadIdx.x & 63, wid = threadIdx.x >> 6;
    if (lane == 0) s[wid] = v;
    __syncthreads();
    if (threadIdx.x == 0) {
        float V = (s[0] + s[1]) + (s[2] + s[3]);
        float T = 0.f;
        for (int i = 0; i < nt; ++i) T += tpart[i];
        out[0] = 0.5f * T - V;
    }
}

extern "C" void kernel_launch(void* const* d_in, const int* in_sizes, int n_in,
                              void* d_out, int out_size, void* d_ws, size_t ws_size,
                              hipStream_t stream) {
    const float* q        = (const float*)d_in[0];
    const float* qd       = (const float*)d_in[1];
    const float* x0       = (const float*)d_in[2];
    const int*   free_idx = (const int*)d_in[3];
    float* out = (float*)d_out;

    float* ws = (float*)d_ws;
    float* X = ws;
    float* Y = ws + NATOMS;
    float* Z = ws + 2 * NATOMS;
    constexpr int NVBLK = (NATOMS / TI) * (NATOMS / JT);  // 8 * 128 = 1024
    constexpr int NTBLK = NFREE / TPB;                    // 16
    float* vpart = ws + 3 * NATOMS;
    float* tpart = vpart + NVBLK;

    build_x<<<NATOMS / TPB, TPB, 0, stream>>>(x0, X, Y, Z);
    scatter_q_and_T<<<NTBLK, TPB, 0, stream>>>(q, qd, free_idx, X, Y, Z, tpart);
    pair_kernel<<<dim3(NATOMS / TI, NATOMS / JT), TPB, 0, stream>>>(X, Y, Z, vpart);
    finalize<<<1, TPB, 0, stream>>>(vpart, NVBLK, tpart, NTBLK, out);
}